// Round 6
// baseline (222.839 us; speedup 1.0000x reference)
//
#include <hip/hip_runtime.h>

#define BATCH 16384
#define DIM 4096
#define G 64
#define PPB 8          // pairs per block
#define THREADS 1024

typedef float f32x4 __attribute__((ext_vector_type(4)));

__device__ __forceinline__ unsigned int bf16_rne(float f) {
    unsigned int u = __builtin_bit_cast(unsigned int, f);
    return (u + 0x7FFFu + ((u >> 16) & 1u)) >> 16;
}

// Block = one pair-group of 8 pairs; grids staged in 128 KiB static LDS as
// packed bf16 (ch1<<16 | ch0): one ds_read_b32 per corner -> both channels.
// Block covers 16 consecutive x/out columns; wave = 16 rows x 64B chunks.
// Grid = 256 blocks (1/CU); Y read from HBM exactly once.
// Main loop: 2 independent row-passes per iteration + prefetch both next
// loads -> ~2-4 KB in flight per wave to cover nt-load HBM latency.
__global__ __launch_bounds__(THREADS) void pair_bilinear_kernel(
    const float* __restrict__ x,
    const float* __restrict__ Y,
    float* __restrict__ out)
{
    __shared__ unsigned int ylds[PPB * G * G];   // 32768 words = 128 KiB
    const int pg  = blockIdx.x;                  // pair-group 0..255
    const int tid = threadIdx.x;

    // ---- stage: Y[pg*8 .. pg*8+7][2][64][64] f32 -> packed bf16 LDS ----
    const float* Yb = Y + (size_t)pg * (PPB * 2 * G * G);
    #pragma unroll
    for (int it = 0; it < (PPB * G * G) / THREADS; ++it) {
        const int w   = it * THREADS + tid;      // word index 0..32767
        const int pl  = w >> 12;                 // pair-local 0..7
        const int pos = w & 4095;                // node 0..4095
        const float c0 = Yb[pl * 8192 + pos];
        const float c1 = Yb[pl * 8192 + 4096 + pos];
        ylds[w] = bf16_rne(c0) | (bf16_rne(c1) << 16);
    }
    __syncthreads();

    // ---- main: stream rows, 2 passes per iteration ----
    const int seg  = tid & 3;                    // which float4 of the 64B
    const int row0 = tid >> 2;                   // 0..255
    const size_t col  = (size_t)pg * 16 + seg * 4;
    const size_t step = (size_t)(THREADS / 4) * DIM;  // 256 rows

    size_t off = (size_t)row0 * DIM + col;
    f32x4 a = __builtin_nontemporal_load(reinterpret_cast<const f32x4*>(x + off));
    f32x4 b = __builtin_nontemporal_load(reinterpret_cast<const f32x4*>(x + off + step));

    const int NITER = BATCH / (2 * (THREADS / 4));   // 32
    for (int it = 0; it < NITER; ++it) {
        const size_t offn = off + 2 * step;
        f32x4 an, bn;
        if (it + 1 < NITER) {
            an = __builtin_nontemporal_load(reinterpret_cast<const f32x4*>(x + offn));
            bn = __builtin_nontemporal_load(reinterpret_cast<const f32x4*>(x + offn + step));
        }

        #pragma unroll
        for (int h = 0; h < 2; ++h) {
            const f32x4 xv = (h == 0) ? a : b;
            const size_t o = off + (size_t)h * step;
            f32x4 ov;
            #pragma unroll
            for (int k = 0; k < 2; ++k) {
                const float u = fminf(fmaxf(xv[2 * k], 0.0f), 1.0f) * (float)(G - 1);
                const float v = fminf(fmaxf(xv[2 * k + 1], 0.0f), 1.0f) * (float)(G - 1);
                const int i0 = min((int)u, G - 2);
                const int j0 = min((int)v, G - 2);
                const float fu = u - (float)i0;
                const float fv = v - (float)j0;

                const int adr = ((seg * 2 + k) << 12) + i0 * G + j0;
                const unsigned int w00 = ylds[adr];
                const unsigned int w01 = ylds[adr + 1];
                const unsigned int w10 = ylds[adr + G];
                const unsigned int w11 = ylds[adr + G + 1];

                const float c000 = __uint_as_float(w00 << 16);
                const float c001 = __uint_as_float(w01 << 16);
                const float c010 = __uint_as_float(w10 << 16);
                const float c011 = __uint_as_float(w11 << 16);
                const float c100 = __uint_as_float(w00 & 0xFFFF0000u);
                const float c101 = __uint_as_float(w01 & 0xFFFF0000u);
                const float c110 = __uint_as_float(w10 & 0xFFFF0000u);
                const float c111 = __uint_as_float(w11 & 0xFFFF0000u);

                const float t0 = c000 + fv * (c001 - c000);
                const float b0 = c010 + fv * (c011 - c010);
                const float t1 = c100 + fv * (c101 - c100);
                const float b1 = c110 + fv * (c111 - c110);
                ov[2 * k]     = t0 + fu * (b0 - t0);
                ov[2 * k + 1] = t1 + fu * (b1 - t1);
            }
            __builtin_nontemporal_store(ov, reinterpret_cast<f32x4*>(out + o));
        }

        off = offn;
        a = an;
        b = bn;
    }
}

extern "C" void kernel_launch(void* const* d_in, const int* in_sizes, int n_in,
                              void* d_out, int out_size, void* d_ws, size_t ws_size,
                              hipStream_t stream) {
    const float* x = (const float*)d_in[0];
    const float* Y = (const float*)d_in[1];
    float* out     = (float*)d_out;

    // 2048 pairs / 8 per block = 256 blocks (one per CU)
    pair_bilinear_kernel<<<256, THREADS, 0, stream>>>(x, Y, out);
}

// Round 8
// 175.291 us; speedup vs baseline: 1.2712x; 1.2712x over previous
//
#include <hip/hip_runtime.h>

#define BATCH 16384
#define DIM 4096
#define G 64
#define PPB 8          // pairs per block -> 128 KiB LDS, 1 block/CU
#define THREADS 1024

typedef float f32x4 __attribute__((ext_vector_type(4)));

__device__ __forceinline__ unsigned int bf16_rne(float f) {
    unsigned int u = __builtin_bit_cast(unsigned int, f);
    return (u + 0x7FFFu + ((u >> 16) & 1u)) >> 16;
}

// Block = 8 pairs (16 x/out columns = 64B per row); grids in 128 KiB LDS as
// packed bf16 (ch1<<16 | ch0): one ds_read_b32 per corner -> both channels.
// Grid = 256 blocks (1/CU); Y read from HBM exactly once.
// Main loop: depth-4 software pipeline on the x stream (named registers,
// static indexing) so ~900-cycle HBM load latency is fully covered by
// ~4 iterations of compute. R6 showed depth-2 (~480 cyc) was insufficient.
__global__ __launch_bounds__(THREADS) void pair_bilinear_kernel(
    const float* __restrict__ x,
    const float* __restrict__ Y,
    float* __restrict__ out)
{
    __shared__ unsigned int ylds[PPB * G * G];   // 32768 words = 128 KiB
    const int pg  = blockIdx.x;                  // pair-group 0..255
    const int tid = threadIdx.x;

    // ---- stage: Y[pg*8 .. pg*8+7][2][64][64] f32 -> packed bf16 LDS ----
    const float* Yb = Y + (size_t)pg * (PPB * 2 * G * G);
    #pragma unroll
    for (int it = 0; it < (PPB * G * G) / THREADS; ++it) {
        const int w   = it * THREADS + tid;      // word index 0..32767
        const int pl  = w >> 12;                 // pair-local 0..7
        const int pos = w & 4095;                // node 0..4095
        const float c0 = Yb[pl * 8192 + pos];
        const float c1 = Yb[pl * 8192 + 4096 + pos];
        ylds[w] = bf16_rne(c0) | (bf16_rne(c1) << 16);
    }
    __syncthreads();

    // ---- main: stream rows, depth-4 pipelined ----
    const int seg  = tid & 3;                    // which float4 of the 64B
    const int row0 = tid >> 2;                   // 0..255
    const size_t col  = (size_t)pg * 16 + seg * 4;
    const size_t step = (size_t)256 * DIM;       // 256 rows

#define COMPUTE_STORE(pv, optr)                                               \
    {                                                                         \
        f32x4 ov;                                                             \
        _Pragma("unroll")                                                     \
        for (int k = 0; k < 2; ++k) {                                         \
            const float u = fminf(fmaxf((pv)[2 * k], 0.0f), 1.0f) * (float)(G - 1); \
            const float v = fminf(fmaxf((pv)[2 * k + 1], 0.0f), 1.0f) * (float)(G - 1); \
            const int i0 = min((int)u, G - 2);                                \
            const int j0 = min((int)v, G - 2);                                \
            const float fu = u - (float)i0;                                   \
            const float fv = v - (float)j0;                                   \
            const int adr = ((seg * 2 + k) << 12) + i0 * G + j0;              \
            const unsigned int w00 = ylds[adr];                               \
            const unsigned int w01 = ylds[adr + 1];                           \
            const unsigned int w10 = ylds[adr + G];                           \
            const unsigned int w11 = ylds[adr + G + 1];                       \
            const float c000 = __uint_as_float(w00 << 16);                    \
            const float c001 = __uint_as_float(w01 << 16);                    \
            const float c010 = __uint_as_float(w10 << 16);                    \
            const float c011 = __uint_as_float(w11 << 16);                    \
            const float c100 = __uint_as_float(w00 & 0xFFFF0000u);            \
            const float c101 = __uint_as_float(w01 & 0xFFFF0000u);            \
            const float c110 = __uint_as_float(w10 & 0xFFFF0000u);            \
            const float c111 = __uint_as_float(w11 & 0xFFFF0000u);            \
            const float t0 = c000 + fv * (c001 - c000);                       \
            const float b0 = c010 + fv * (c011 - c010);                       \
            const float t1 = c100 + fv * (c101 - c100);                       \
            const float b1 = c110 + fv * (c111 - c110);                       \
            ov[2 * k]     = t0 + fu * (b0 - t0);                              \
            ov[2 * k + 1] = t1 + fu * (b1 - t1);                              \
        }                                                                     \
        __builtin_nontemporal_store(ov, reinterpret_cast<f32x4*>(optr));      \
    }

    const float* xp = x + (size_t)row0 * DIM + col;
    float*       op = out + (size_t)row0 * DIM + col;

    f32x4 p0 = *reinterpret_cast<const f32x4*>(xp);
    f32x4 p1 = *reinterpret_cast<const f32x4*>(xp + step);
    f32x4 p2 = *reinterpret_cast<const f32x4*>(xp + 2 * step);
    f32x4 p3 = *reinterpret_cast<const f32x4*>(xp + 3 * step);

    // 64 row-passes total = 16 groups of 4; steady state keeps 4 loads ahead.
    for (int g = 0; g < 15; ++g) {
        const f32x4 n0 = *reinterpret_cast<const f32x4*>(xp + 4 * step);
        const f32x4 n1 = *reinterpret_cast<const f32x4*>(xp + 5 * step);
        const f32x4 n2 = *reinterpret_cast<const f32x4*>(xp + 6 * step);
        const f32x4 n3 = *reinterpret_cast<const f32x4*>(xp + 7 * step);

        COMPUTE_STORE(p0, op)
        COMPUTE_STORE(p1, op + step)
        COMPUTE_STORE(p2, op + 2 * step)
        COMPUTE_STORE(p3, op + 3 * step)

        p0 = n0; p1 = n1; p2 = n2; p3 = n3;
        xp += 4 * step;
        op += 4 * step;
    }
    // epilogue group (no prefetch)
    COMPUTE_STORE(p0, op)
    COMPUTE_STORE(p1, op + step)
    COMPUTE_STORE(p2, op + 2 * step)
    COMPUTE_STORE(p3, op + 3 * step)

#undef COMPUTE_STORE
}

extern "C" void kernel_launch(void* const* d_in, const int* in_sizes, int n_in,
                              void* d_out, int out_size, void* d_ws, size_t ws_size,
                              hipStream_t stream) {
    const float* x = (const float*)d_in[0];
    const float* Y = (const float*)d_in[1];
    float* out     = (float*)d_out;

    // 2048 pairs / 8 per block = 256 blocks (one per CU)
    pair_bilinear_kernel<<<256, THREADS, 0, stream>>>(x, Y, out);
}